// Round 14
// baseline (672.198 us; speedup 1.0000x reference)
//
#include <hip/hip_runtime.h>

typedef __bf16 bf16x8 __attribute__((ext_vector_type(8)));
typedef float f32x4 __attribute__((ext_vector_type(4)));

__device__ __forceinline__ unsigned short f2bf(float x) {
  union { float f; unsigned int u; } c; c.f = x;
  unsigned int r = c.u + 0x7FFFu + ((c.u >> 16) & 1u);
  return (unsigned short)(r >> 16);
}

// ---------------- convert f32 -> bf16 (vectorized) ----------------
__global__ __launch_bounds__(256) void f32_to_bf16_vec4(
    const float* __restrict__ in, unsigned short* __restrict__ out, int n4) {
  int i = blockIdx.x * blockDim.x + threadIdx.x;
  int stride = gridDim.x * blockDim.x;
  const float4* in4 = (const float4*)in;
  ushort4* out4 = (ushort4*)out;
  for (; i < n4; i += stride) {
    float4 f = in4[i];
    ushort4 u;
    u.x = f2bf(f.x); u.y = f2bf(f.y); u.z = f2bf(f.z); u.w = f2bf(f.w);
    out4[i] = u;
  }
}

// ---------------- fuse rel-pos bias + window mask: M[w][h][q][k] ----------------
__global__ __launch_bounds__(256) void build_bias_mask(
    const float* __restrict__ bias_table,  // [127][16]
    const float* __restrict__ mask,        // [64][64][64]
    float* __restrict__ M) {               // [64][16][64][64]
  const int idx = blockIdx.x * 256 + threadIdx.x;
  const int k = idx & 63, q = (idx >> 6) & 63, h = (idx >> 12) & 15, w = idx >> 16;
  M[idx] = bias_table[(q - k + 63) * 16 + h] + mask[(w * 64 + q) * 64 + k];
}

#define GLOAD_LDS16(gp, lp)                                                          \
  __builtin_amdgcn_global_load_lds(                                                  \
      (const __attribute__((address_space(1))) unsigned int*)(uintptr_t)(gp),        \
      (__attribute__((address_space(3))) unsigned int*)(uintptr_t)(lp), 16, 0, 0)

// ---------------- 128x128 GEMM, 16x16x32 MFMA, 2 blocks/CU, simple dbuf schedule ----
// A: MxK bf16 row-major, B: NxK bf16 row-major. K=512. 256 threads = 4 waves (2M x 2N),
// wave tile 64x64. LDS 64KB (A[2][128][64] | B[2][128][64], XOR-swizzled) -> 2 blocks/CU:
// cross-block wave overlap hides the per-tile vmcnt(0)+barrier drain (m103/m114 mechanism).
// EPI: 0 = f32 row-major out (C0, ldc); 2 = qkv-split head-blocked bf16 out (C0=Q,C1=K,C2=V)
template <int NBN, int EPI>
__global__ __launch_bounds__(256, 2) void gemm128(
    const unsigned short* __restrict__ A,
    const unsigned short* __restrict__ B,
    const float* __restrict__ bias,
    void* __restrict__ C0, void* __restrict__ C1, void* __restrict__ C2,
    int ldc) {
  constexpr int K = 512;
  constexpr int NT = K / 64;  // 8 K-tiles
  __shared__ __attribute__((aligned(128))) char lds[65536];  // A:2x16KB | B:2x16KB

  const int t = threadIdx.x;
  const int lane = t & 63;
  const int wid = t >> 6;                 // 0..3
  const int wr = wid >> 1, wc = wid & 1;  // 2 x 2 waves
  const int lr = lane & 15, lg = lane >> 4;

  const int nwg = gridDim.x;
  const int cpx = nwg >> 3;
  const int wgid = (blockIdx.x & 7) * cpx + (blockIdx.x >> 3);
  const int bm = wgid / NBN, bn = wgid % NBN;
  const int m0 = bm * 128, n0 = bn * 128;

  const char* Ab = (const char*)(A + (size_t)m0 * K);
  const char* Bb = (const char*)(B + (size_t)n0 * K);

  const int r3 = t >> 3, ps = t & 7;  // 32 rows x 8 chunks of 16B per issue

  // staging: issue i covers rows i*32 + r3; src col chunk pre-swizzled (ps^(row&7))
  unsigned soff[4], adst[4], bdst[4];
#pragma unroll
  for (int i = 0; i < 4; ++i) {
    const int row = i * 32 + r3;
    soff[i] = (unsigned)((row * K + ((ps ^ (row & 7)) << 3)) * 2);
    adst[i] = (unsigned)(row * 128 + ps * 16);
    bdst[i] = (unsigned)(32768 + row * 128 + ps * 16);
  }

#define STAGE(tt, buf)                                                          \
  do {                                                                          \
    _Pragma("unroll") for (int i = 0; i < 4; ++i)                               \
      GLOAD_LDS16(Ab + soff[i] + (tt)*128, lds + (buf)*16384 + adst[i]);        \
    _Pragma("unroll") for (int i = 0; i < 4; ++i)                               \
      GLOAD_LDS16(Bb + soff[i] + (tt)*128, lds + (buf)*16384 + bdst[i]);        \
  } while (0)

  // fragment read bases (conflict-free: row = lr, chunk = kk*4+lg, XOR row&7)
  unsigned abase[2], bbase[2];
#pragma unroll
  for (int kk = 0; kk < 2; ++kk) {
    const unsigned swz = (unsigned)(((kk * 4 + lg) ^ (lr & 7)) << 4);
    abase[kk] = (unsigned)((wr * 64 + lr) * 128) + swz;
    bbase[kk] = (unsigned)(32768 + (wc * 64 + lr) * 128) + swz;
  }

  f32x4 acc[4][4];
#pragma unroll
  for (int i = 0; i < 4; ++i)
#pragma unroll
    for (int j = 0; j < 4; ++j) acc[i][j] = f32x4{0.f, 0.f, 0.f, 0.f};

  // prologue: tile0 -> buf0
  STAGE(0, 0);
  asm volatile("s_waitcnt vmcnt(0)" ::: "memory");
  __builtin_amdgcn_s_barrier();

#pragma unroll
  for (int tt = 0; tt < NT; ++tt) {
    const int buf = tt & 1;
    const int nb = buf ^ 1;
    if (tt + 1 < NT) STAGE(tt + 1, nb);  // issue early; drained at tail vmcnt(0)
    bf16x8 af[4][2], bfr[4][2];
#pragma unroll
    for (int mt = 0; mt < 4; ++mt)
#pragma unroll
      for (int kk = 0; kk < 2; ++kk)
        af[mt][kk] = *(const bf16x8*)(lds + buf * 16384 + abase[kk] + mt * 2048);
#pragma unroll
    for (int nt = 0; nt < 4; ++nt)
#pragma unroll
      for (int kk = 0; kk < 2; ++kk)
        bfr[nt][kk] = *(const bf16x8*)(lds + buf * 16384 + bbase[kk] + nt * 2048);
    asm volatile("s_waitcnt lgkmcnt(0)" ::: "memory");
    __builtin_amdgcn_sched_barrier(0);
    __builtin_amdgcn_s_setprio(1);
#pragma unroll
    for (int mt = 0; mt < 4; ++mt)
#pragma unroll
      for (int nt = 0; nt < 4; ++nt)
#pragma unroll
        for (int kk = 0; kk < 2; ++kk)
          acc[mt][nt] = __builtin_amdgcn_mfma_f32_16x16x32_bf16(
              af[mt][kk], bfr[nt][kk], acc[mt][nt], 0, 0, 0);
    __builtin_amdgcn_s_setprio(0);
    if (tt + 1 < NT) asm volatile("s_waitcnt vmcnt(0)" ::: "memory");
    __builtin_amdgcn_s_barrier();
  }
#undef STAGE

  // epilogue: 16x16 C/D layout: col = lr, row = lg*4 + r
#pragma unroll
  for (int mt = 0; mt < 4; ++mt)
#pragma unroll
    for (int nt = 0; nt < 4; ++nt) {
      const int n = n0 + wc * 64 + nt * 16 + lr;
      const float bv = bias[n];
      const f32x4 a4 = acc[mt][nt];
      if constexpr (EPI == 2) {
        const int part = n >> 9;
        unsigned short* dst = part == 0 ? (unsigned short*)C0
                               : (part == 1 ? (unsigned short*)C1 : (unsigned short*)C2);
        const float sc = (part == 0) ? 0.17677669529663687f : 1.0f;
        const int hh = (n >> 5) & 15, dd = n & 31;
#pragma unroll
        for (int r = 0; r < 4; ++r) {
          const int m = m0 + wr * 64 + mt * 16 + lg * 4 + r;
          dst[((size_t)((m >> 6) * 16 + hh) * 64 + (m & 63)) * 32 + dd] =
              f2bf((a4[r] + bv) * sc);
        }
      } else {
#pragma unroll
        for (int r = 0; r < 4; ++r) {
          const int m = m0 + wr * 64 + mt * 16 + lg * 4 + r;
          ((float*)C0)[(size_t)m * ldc + n] = a4[r] + bv;
        }
      }
    }
}

// ---------------- fused window attention v3 + setprio + window-paired blocks ----------------
// 128 threads = 2 waves; both waves share (window, head): wave p handles b = bbase + 64p.
// (b+64)&63 == b&63 -> same M slice (16KB, L1-resident) for both waves.
__global__ __launch_bounds__(128) void attn_kernel(
    const unsigned short* __restrict__ Qh,  // [32768][64][32] bf16, pre-scaled
    const unsigned short* __restrict__ Kh,  // [32768][64][32]
    const unsigned short* __restrict__ Vh,  // [32768][64][32]
    const float* __restrict__ M,            // [64][16][64][64] fused bias+mask
    unsigned short* __restrict__ attn_out   // [131072][512] bf16, col = h*32+d
) {
  const int wv = threadIdx.x >> 6;
  const int idx = blockIdx.x;            // 0..16383
  const int h = idx & 15;
  const int g = idx >> 4;                // 0..1023
  const int b = (g & 63) + ((g >> 6) << 7) + (wv << 6);
  const int bh = b * 16 + h;
  const int lane = threadIdx.x & 63;
  const int lr = lane & 15, lg = lane >> 4;

  __shared__ unsigned short VtS[2][32 * 72];  // V^T per wave: [d][k], stride 72
  __shared__ unsigned short PlS[2][16 * 72];  // P-slice per wave: [16 q][k]
  unsigned short* Vt = VtS[wv];
  unsigned short* Pl = PlS[wv];

  const unsigned short* qb = Qh + (size_t)bh * 2048;
  const unsigned short* kb = Kh + (size_t)bh * 2048;
  const unsigned short* vg = Vh + (size_t)bh * 2048;

  bf16x8 vr[4];
#pragma unroll
  for (int i = 0; i < 4; ++i) vr[i] = ((const bf16x8*)(vg + lane * 32))[i];
  bf16x8 kf[4], qf[4];
#pragma unroll
  for (int nt = 0; nt < 4; ++nt)
    kf[nt] = *(const bf16x8*)(kb + (nt * 16 + lr) * 32 + lg * 8);
#pragma unroll
  for (int mt = 0; mt < 4; ++mt)
    qf[mt] = *(const bf16x8*)(qb + (mt * 16 + lr) * 32 + lg * 8);

  {
    __bf16* vt = (__bf16*)Vt;
#pragma unroll
    for (int d = 0; d < 8; ++d) {
      vt[(d)*72 + lane] = vr[0][d];
      vt[(d + 8) * 72 + lane] = vr[1][d];
      vt[(d + 16) * 72 + lane] = vr[2][d];
      vt[(d + 24) * 72 + lane] = vr[3][d];
    }
  }
  bf16x8 vfrag[2][2];
#pragma unroll
  for (int dt = 0; dt < 2; ++dt)
#pragma unroll
    for (int ki = 0; ki < 2; ++ki)
      vfrag[dt][ki] = *(const bf16x8*)(Vt + (dt * 16 + lr) * 72 + ki * 32 + lg * 8);

  const float* Mb = M + (size_t)((b & 63) * 16 + h) * 4096;

  f32x4 o[4][2];
#pragma unroll
  for (int i = 0; i < 4; ++i)
#pragma unroll
    for (int j = 0; j < 2; ++j) o[i][j] = f32x4{0.f, 0.f, 0.f, 0.f};
  float rinv[4][4];

#pragma unroll
  for (int mt = 0; mt < 4; ++mt) {
    // coalesced M reads (lanes 0-15 contiguous per (r,nt)); shared slice -> L1-hot
    float mv[4][4];
#pragma unroll
    for (int r = 0; r < 4; ++r)
#pragma unroll
      for (int nt = 0; nt < 4; ++nt)
        mv[r][nt] = Mb[(mt * 16 + lg * 4 + r) * 64 + nt * 16 + lr];

    f32x4 s[4];
#pragma unroll
    for (int nt = 0; nt < 4; ++nt) s[nt] = f32x4{0.f, 0.f, 0.f, 0.f};
    __builtin_amdgcn_s_setprio(1);
#pragma unroll
    for (int nt = 0; nt < 4; ++nt)
      s[nt] = __builtin_amdgcn_mfma_f32_16x16x32_bf16(qf[mt], kf[nt], s[nt], 0, 0, 0);
    __builtin_amdgcn_s_setprio(0);

    // v3 softmax: max-sub; sum/rcp OFF the P path (P unnormalized, rinv applied at end)
#pragma unroll
    for (int r = 0; r < 4; ++r) {
      float v[4];
#pragma unroll
      for (int nt = 0; nt < 4; ++nt) v[nt] = s[nt][r] + mv[r][nt];
      float mx = fmaxf(fmaxf(v[0], v[1]), fmaxf(v[2], v[3]));
      mx = fmaxf(mx, __shfl_xor(mx, 1, 64));
      mx = fmaxf(mx, __shfl_xor(mx, 2, 64));
      mx = fmaxf(mx, __shfl_xor(mx, 4, 64));
      mx = fmaxf(mx, __shfl_xor(mx, 8, 64));
      float sum = 0.f;
#pragma unroll
      for (int nt = 0; nt < 4; ++nt) {
        v[nt] = __expf(v[nt] - mx);
        sum += v[nt];
      }
      sum += __shfl_xor(sum, 1, 64);
      sum += __shfl_xor(sum, 2, 64);
      sum += __shfl_xor(sum, 4, 64);
      sum += __shfl_xor(sum, 8, 64);
      rinv[mt][r] = __builtin_amdgcn_rcpf(sum);
#pragma unroll
      for (int nt = 0; nt < 4; ++nt)
        Pl[(lg * 4 + r) * 72 + nt * 16 + lr] = f2bf(v[nt]);
    }

    // PV (in-order DS pipe: same-wave reads follow writes)
    bf16x8 pa[2];
#pragma unroll
    for (int ki = 0; ki < 2; ++ki)
      pa[ki] = *(const bf16x8*)(Pl + lr * 72 + ki * 32 + lg * 8);
    __builtin_amdgcn_s_setprio(1);
#pragma unroll
    for (int dt = 0; dt < 2; ++dt)
#pragma unroll
      for (int ki = 0; ki < 2; ++ki)
        o[mt][dt] = __builtin_amdgcn_mfma_f32_16x16x32_bf16(pa[ki], vfrag[dt][ki], o[mt][dt], 0, 0, 0);
    __builtin_amdgcn_s_setprio(0);
  }

#pragma unroll
  for (int mt = 0; mt < 4; ++mt) {
#pragma unroll
    for (int r = 0; r < 4; ++r) {
      const int m = mt * 16 + lg * 4 + r;
      const float ri = rinv[mt][r];
#pragma unroll
      for (int dt = 0; dt < 2; ++dt) {
        const int d = dt * 16 + lr;
        attn_out[(size_t)(b * 64 + m) * 512 + h * 32 + d] = f2bf(o[mt][dt][r] * ri);
      }
    }
  }
}

// ---------------- launch ----------------
extern "C" void kernel_launch(void* const* d_in, const int* in_sizes, int n_in,
                              void* d_out, int out_size, void* d_ws, size_t ws_size,
                              hipStream_t stream) {
  const float* X = (const float*)d_in[0];
  const float* mask = (const float*)d_in[1];
  const float* qkv_w = (const float*)d_in[2];
  const float* qkv_b = (const float*)d_in[3];
  const float* proj_w = (const float*)d_in[4];
  const float* proj_b = (const float*)d_in[5];
  const float* bias_table = (const float*)d_in[6];
  float* out = (float*)d_out;
  char* ws = (char*)d_ws;

  // workspace layout (bytes)
  unsigned short* Xb      = (unsigned short*)(ws);                 // 134,217,728
  unsigned short* Qh      = (unsigned short*)(ws + 134217728ull);  // 134,217,728
  unsigned short* Kh      = (unsigned short*)(ws + 268435456ull);  // 134,217,728
  unsigned short* Vh      = (unsigned short*)(ws + 402653184ull);  // 134,217,728
  unsigned short* attnout = (unsigned short*)(ws + 536870912ull);  // 134,217,728
  unsigned short* qkv_wb  = (unsigned short*)(ws + 671088640ull);  // 1,572,864
  unsigned short* proj_wb = (unsigned short*)(ws + 672661504ull);  // 524,288
  float*          Mf      = (float*)(ws + 673185792ull);           // 16,777,216

  f32_to_bf16_vec4<<<2048, 256, 0, stream>>>(X, Xb, 67108864 / 4);
  f32_to_bf16_vec4<<<768, 256, 0, stream>>>(qkv_w, qkv_wb, 786432 / 4);
  f32_to_bf16_vec4<<<256, 256, 0, stream>>>(proj_w, proj_wb, 262144 / 4);
  build_bias_mask<<<16384, 256, 0, stream>>>(bias_table, mask, Mf);

  // QKV: M=131072, N=1536, K=512 -> head-blocked Q/K/V bf16; grid 1024*12 = 12288
  gemm128<12, 2><<<12288, 256, 0, stream>>>(Xb, qkv_wb, qkv_b, (void*)Qh, (void*)Kh, (void*)Vh, 1536);

  // attention: 2 waves per block, window-paired (b, b+64) share the M slice
  attn_kernel<<<16384, 128, 0, stream>>>(Qh, Kh, Vh, Mf, attnout);

  // proj: M=131072, N=512, K=512 -> d_out f32; grid 1024*4 = 4096
  gemm128<4, 0><<<4096, 256, 0, stream>>>(attnout, proj_wb, proj_b, (void*)out, nullptr, nullptr, 512);
}

// Round 15
// 581.708 us; speedup vs baseline: 1.1556x; 1.1556x over previous
//
#include <hip/hip_runtime.h>

typedef __bf16 bf16x8 __attribute__((ext_vector_type(8)));
typedef float f32x4 __attribute__((ext_vector_type(4)));

__device__ __forceinline__ unsigned short f2bf(float x) {
  union { float f; unsigned int u; } c; c.f = x;
  unsigned int r = c.u + 0x7FFFu + ((c.u >> 16) & 1u);
  return (unsigned short)(r >> 16);
}

// ---------------- convert f32 -> bf16 (vectorized) ----------------
__global__ __launch_bounds__(256) void f32_to_bf16_vec4(
    const float* __restrict__ in, unsigned short* __restrict__ out, int n4) {
  int i = blockIdx.x * blockDim.x + threadIdx.x;
  int stride = gridDim.x * blockDim.x;
  const float4* in4 = (const float4*)in;
  ushort4* out4 = (ushort4*)out;
  for (; i < n4; i += stride) {
    float4 f = in4[i];
    ushort4 u;
    u.x = f2bf(f.x); u.y = f2bf(f.y); u.z = f2bf(f.z); u.w = f2bf(f.w);
    out4[i] = u;
  }
}

// ---------------- fuse rel-pos bias + window mask: M[w][h][q][k] ----------------
__global__ __launch_bounds__(256) void build_bias_mask(
    const float* __restrict__ bias_table,  // [127][16]
    const float* __restrict__ mask,        // [64][64][64]
    float* __restrict__ M) {               // [64][16][64][64]
  const int idx = blockIdx.x * 256 + threadIdx.x;
  const int k = idx & 63, q = (idx >> 6) & 63, h = (idx >> 12) & 15, w = idx >> 16;
  M[idx] = bias_table[(q - k + 63) * 16 + h] + mask[(w * 64 + q) * 64 + k];
}

#define GLOAD_LDS16(gp, lp)                                                          \
  __builtin_amdgcn_global_load_lds(                                                  \
      (const __attribute__((address_space(1))) unsigned int*)(uintptr_t)(gp),        \
      (__attribute__((address_space(3))) unsigned int*)(uintptr_t)(lp), 16, 0, 0)

// ---------------- 256x256 GEMM, 16x16x32 MFMA, 4 phases/K-tile (round-5 schedule) ----
// EPI: 0 = f32 row-major out (C0, ldc); 2 = qkv-split head-blocked bf16 out (C0=Q,C1=K,C2=V)
template <int NBN, int EPI>
__global__ __launch_bounds__(512, 2) void gemm256(
    const unsigned short* __restrict__ A,
    const unsigned short* __restrict__ B,
    const float* __restrict__ bias,
    void* __restrict__ C0, void* __restrict__ C1, void* __restrict__ C2,
    int ldc) {
  constexpr int K = 512;
  constexpr int NT = K / 64;  // 8 K-tiles
  __shared__ __attribute__((aligned(128))) char lds[131072];

  const int t = threadIdx.x;
  const int lane = t & 63;
  const int wid = t >> 6;
  const int wr = wid >> 2, wc = wid & 3;
  const int lr = lane & 15, lg = lane >> 4;

  const int nwg = gridDim.x;
  const int cpx = nwg >> 3;
  const int wgid = (blockIdx.x & 7) * cpx + (blockIdx.x >> 3);
  const int bm = wgid / NBN, bn = wgid % NBN;
  const int m0 = bm * 256, n0 = bn * 256;

  const char* Ab = (const char*)(A + (size_t)m0 * K);
  const char* Bb = (const char*)(B + (size_t)n0 * K);

  const int r3 = t >> 3, ps = t & 7;

  unsigned aoff[2][2], adst[2][2], boff[2][2], bdst[2][2];
#pragma unroll
  for (int j = 0; j < 2; ++j)
#pragma unroll
    for (int i = 0; i < 2; ++i) {
      const int rowA = i * 128 + j * 64 + r3;
      aoff[j][i] = (unsigned)((rowA * K + ((ps ^ (rowA & 7)) << 3)) * 2);
      adst[j][i] = (unsigned)(rowA * 128 + ps * 16);
      const int rowB = i * 128 + ((r3 >> 5) << 6) + j * 32 + (r3 & 31);
      boff[j][i] = (unsigned)((rowB * K + ((ps ^ (rowB & 7)) << 3)) * 2);
      bdst[j][i] = (unsigned)(65536 + rowB * 128 + ps * 16);
    }

#define STAGE_A(j, tt, buf)                                                   \
  do {                                                                        \
    GLOAD_LDS16(Ab + aoff[j][0] + (tt)*128, lds + (buf)*32768 + adst[j][0]);  \
    GLOAD_LDS16(Ab + aoff[j][1] + (tt)*128, lds + (buf)*32768 + adst[j][1]);  \
  } while (0)
#define STAGE_B(j, tt, buf)                                                   \
  do {                                                                        \
    GLOAD_LDS16(Bb + boff[j][0] + (tt)*128, lds + (buf)*32768 + bdst[j][0]);  \
    GLOAD_LDS16(Bb + boff[j][1] + (tt)*128, lds + (buf)*32768 + bdst[j][1]);  \
  } while (0)

  unsigned abase[2], bbase[2];
#pragma unroll
  for (int kk = 0; kk < 2; ++kk) {
    abase[kk] = (unsigned)((wr * 128 + lr) * 128 + (((kk * 4 + lg) ^ (lr & 7)) << 4));
    bbase[kk] = (unsigned)(65536 + (wc * 64 + lr) * 128 + (((kk * 4 + lg) ^ (lr & 7)) << 4));
  }

  f32x4 acc[8][4];
#pragma unroll
  for (int i = 0; i < 8; ++i)
#pragma unroll
    for (int j = 0; j < 4; ++j) acc[i][j] = f32x4{0.f, 0.f, 0.f, 0.f};

#define BAR_IN()                                         \
  __builtin_amdgcn_s_barrier();                          \
  asm volatile("s_waitcnt lgkmcnt(0)" ::: "memory");     \
  __builtin_amdgcn_sched_barrier(0);                     \
  __builtin_amdgcn_s_setprio(1)
#define MFMA16(QM, NTLO)                                                            \
  _Pragma("unroll") for (int mt = 0; mt < 4; ++mt)                                  \
    _Pragma("unroll") for (int nt = 0; nt < 2; ++nt)                                \
      _Pragma("unroll") for (int kk = 0; kk < 2; ++kk)                              \
        acc[(QM)*4 + mt][(NTLO) + nt] = __builtin_amdgcn_mfma_f32_16x16x32_bf16(    \
            af[mt][kk], bfr[(NTLO) + nt][kk], acc[(QM)*4 + mt][(NTLO) + nt], 0, 0, 0)

  // prologue: UA0(t0) UB0(t0) UB1(t0) UA1(t0) UA0(t1) UB0(t1)  (12 loads)
  STAGE_A(0, 0, 0); STAGE_B(0, 0, 0); STAGE_B(1, 0, 0); STAGE_A(1, 0, 0);
  STAGE_A(0, 1, 1); STAGE_B(0, 1, 1);
  asm volatile("s_waitcnt vmcnt(8)" ::: "memory");
  __builtin_amdgcn_s_barrier();

  // Deaths (tile tt, buf): UA0,UB0 after p0; UB1 after p1; UA1 after p2.
  // Stage: p0->UB1(tt+1,nb), p1->UA1(tt+1,nb), p2->UA0(tt+2,buf), p3->UB0(tt+2,buf).
#pragma unroll
  for (int tt = 0; tt < NT; ++tt) {
    const int buf = tt & 1;
    const int nb = buf ^ 1;
    bf16x8 af[4][2], bfr[4][2];
    // ---- p0 ----
#pragma unroll
    for (int nt = 0; nt < 2; ++nt)
#pragma unroll
      for (int kk = 0; kk < 2; ++kk)
        bfr[nt][kk] = *(const bf16x8*)(lds + buf * 32768 + bbase[kk] + nt * 2048);
#pragma unroll
    for (int mt = 0; mt < 4; ++mt)
#pragma unroll
      for (int kk = 0; kk < 2; ++kk)
        af[mt][kk] = *(const bf16x8*)(lds + buf * 32768 + abase[kk] + mt * 2048);
    if (tt + 1 < NT) STAGE_B(1, tt + 1, nb);
    BAR_IN();
    MFMA16(0, 0);
    __builtin_amdgcn_s_setprio(0);
    if (tt == NT - 1) asm volatile("s_waitcnt vmcnt(2)" ::: "memory");
    else              asm volatile("s_waitcnt vmcnt(8)" ::: "memory");
    __builtin_amdgcn_s_barrier();
    // ---- p1 ----
#pragma unroll
    for (int nt = 2; nt < 4; ++nt)
#pragma unroll
      for (int kk = 0; kk < 2; ++kk)
        bfr[nt][kk] = *(const bf16x8*)(lds + buf * 32768 + bbase[kk] + nt * 2048);
    if (tt + 1 < NT) STAGE_A(1, tt + 1, nb);
    BAR_IN();
    MFMA16(0, 2);
    __builtin_amdgcn_s_setprio(0);
    if (tt == NT - 1) asm volatile("s_waitcnt vmcnt(0)" ::: "memory");
    else              asm volatile("s_waitcnt vmcnt(8)" ::: "memory");
    __builtin_amdgcn_s_barrier();
    // ---- p2 ----
#pragma unroll
    for (int mt = 0; mt < 4; ++mt)
#pragma unroll
      for (int kk = 0; kk < 2; ++kk)
        af[mt][kk] = *(const bf16x8*)(lds + buf * 32768 + abase[kk] + 8192 + mt * 2048);
    if (tt + 2 < NT) STAGE_A(0, tt + 2, buf);
    BAR_IN();
    MFMA16(1, 0);
    __builtin_amdgcn_s_setprio(0);
    if (tt < NT - 1) asm volatile("s_waitcnt vmcnt(8)" ::: "memory");
    __builtin_amdgcn_s_barrier();
    // ---- p3 ----
    if (tt + 2 < NT) STAGE_B(0, tt + 2, buf);
    BAR_IN();
    MFMA16(1, 2);
    __builtin_amdgcn_s_setprio(0);
    if (tt < NT - 2)       asm volatile("s_waitcnt vmcnt(8)" ::: "memory");
    else if (tt == NT - 2) asm volatile("s_waitcnt vmcnt(4)" ::: "memory");
    __builtin_amdgcn_s_barrier();
  }
#undef MFMA16
#undef BAR_IN
#undef STAGE_A
#undef STAGE_B

  // epilogue: 16x16 C/D layout: col = lr, row = lg*4 + r
#pragma unroll
  for (int qm = 0; qm < 2; ++qm)
#pragma unroll
    for (int mt = 0; mt < 4; ++mt)
#pragma unroll
      for (int nt = 0; nt < 4; ++nt) {
        const int n = n0 + wc * 64 + nt * 16 + lr;
        const float bv = bias[n];
        const f32x4 a4 = acc[qm * 4 + mt][nt];
        if constexpr (EPI == 2) {
          const int part = n >> 9;
          unsigned short* dst = part == 0 ? (unsigned short*)C0
                                 : (part == 1 ? (unsigned short*)C1 : (unsigned short*)C2);
          const float sc = (part == 0) ? 0.17677669529663687f : 1.0f;
          const int hh = (n >> 5) & 15, dd = n & 31;
#pragma unroll
          for (int r = 0; r < 4; ++r) {
            const int m = m0 + wr * 128 + qm * 64 + mt * 16 + lg * 4 + r;
            dst[((size_t)((m >> 6) * 16 + hh) * 64 + (m & 63)) * 32 + dd] =
                f2bf((a4[r] + bv) * sc);
          }
        } else {
#pragma unroll
          for (int r = 0; r < 4; ++r) {
            const int m = m0 + wr * 128 + qm * 64 + mt * 16 + lg * 4 + r;
            ((float*)C0)[(size_t)m * ldc + n] = a4[r] + bv;
          }
        }
      }
}

// ---------------- fused window attention v3 + setprio + window-paired blocks ----------------
// 128 threads = 2 waves; both waves share (window, head): wave wv handles b with same b&63.
// -> both waves gather the SAME 16KB M slice (wave 1 hits L1 warm).
__global__ __launch_bounds__(128) void attn_kernel(
    const unsigned short* __restrict__ Qh,  // [32768][64][32] bf16, pre-scaled
    const unsigned short* __restrict__ Kh,  // [32768][64][32]
    const unsigned short* __restrict__ Vh,  // [32768][64][32]
    const float* __restrict__ M,            // [64][16][64][64] fused bias+mask
    unsigned short* __restrict__ attn_out   // [131072][512] bf16, col = h*32+d
) {
  const int wv = threadIdx.x >> 6;
  const int idx = blockIdx.x;            // 0..16383
  const int h = idx & 15;
  const int g = idx >> 4;                // 0..1023
  const int b = (g & 63) + ((g >> 6) << 7) + (wv << 6);  // waves share b&63
  const int bh = b * 16 + h;
  const int lane = threadIdx.x & 63;
  const int lr = lane & 15, lg = lane >> 4;

  __shared__ unsigned short VtS[2][32 * 72];  // V^T per wave: [d][k], stride 72
  __shared__ unsigned short PlS[2][16 * 72];  // P-slice per wave: [16 q][k]
  unsigned short* Vt = VtS[wv];
  unsigned short* Pl = PlS[wv];

  const unsigned short* qb = Qh + (size_t)bh * 2048;
  const unsigned short* kb = Kh + (size_t)bh * 2048;
  const unsigned short* vg = Vh + (size_t)bh * 2048;

  bf16x8 vr[4];
#pragma unroll
  for (int i = 0; i < 4; ++i) vr[i] = ((const bf16x8*)(vg + lane * 32))[i];
  bf16x8 kf[4], qf[4];
#pragma unroll
  for (int nt = 0; nt < 4; ++nt)
    kf[nt] = *(const bf16x8*)(kb + (nt * 16 + lr) * 32 + lg * 8);
#pragma unroll
  for (int mt = 0; mt < 4; ++mt)
    qf[mt] = *(const bf16x8*)(qb + (mt * 16 + lr) * 32 + lg * 8);

  {
    __bf16* vt = (__bf16*)Vt;
#pragma unroll
    for (int d = 0; d < 8; ++d) {
      vt[(d)*72 + lane] = vr[0][d];
      vt[(d + 8) * 72 + lane] = vr[1][d];
      vt[(d + 16) * 72 + lane] = vr[2][d];
      vt[(d + 24) * 72 + lane] = vr[3][d];
    }
  }
  bf16x8 vfrag[2][2];
#pragma unroll
  for (int dt = 0; dt < 2; ++dt)
#pragma unroll
    for (int ki = 0; ki < 2; ++ki)
      vfrag[dt][ki] = *(const bf16x8*)(Vt + (dt * 16 + lr) * 72 + ki * 32 + lg * 8);

  const float* Mb = M + (size_t)((b & 63) * 16 + h) * 4096;

  f32x4 o[4][2];
#pragma unroll
  for (int i = 0; i < 4; ++i)
#pragma unroll
    for (int j = 0; j < 2; ++j) o[i][j] = f32x4{0.f, 0.f, 0.f, 0.f};
  float rinv[4][4];

#pragma unroll
  for (int mt = 0; mt < 4; ++mt) {
    // coalesced M reads (lanes 0-15 contiguous per (r,nt)); shared slice -> L1-hot
    float mv[4][4];
#pragma unroll
    for (int r = 0; r < 4; ++r)
#pragma unroll
      for (int nt = 0; nt < 4; ++nt)
        mv[r][nt] = Mb[(mt * 16 + lg * 4 + r) * 64 + nt * 16 + lr];

    f32x4 s[4];
#pragma unroll
    for (int nt = 0; nt < 4; ++nt) s[nt] = f32x4{0.f, 0.f, 0.f, 0.f};
    __builtin_amdgcn_s_setprio(1);
#pragma unroll
    for (int nt = 0; nt < 4; ++nt)
      s[nt] = __builtin_amdgcn_mfma_f32_16x16x32_bf16(qf[mt], kf[nt], s[nt], 0, 0, 0);
    __builtin_amdgcn_s_setprio(0);

    // v3 softmax: max-sub; sum/rcp OFF the P path (P unnormalized, rinv applied at end)
#pragma unroll
    for (int r = 0; r < 4; ++r) {
      float v[4];
#pragma unroll
      for (int nt = 0; nt < 4; ++nt) v[nt] = s[nt][r] + mv[r][nt];
      float mx = fmaxf(fmaxf(v[0], v[1]), fmaxf(v[2], v[3]));
      mx = fmaxf(mx, __shfl_xor(mx, 1, 64));
      mx = fmaxf(mx, __shfl_xor(mx, 2, 64));
      mx = fmaxf(mx, __shfl_xor(mx, 4, 64));
      mx = fmaxf(mx, __shfl_xor(mx, 8, 64));
      float sum = 0.f;
#pragma unroll
      for (int nt = 0; nt < 4; ++nt) {
        v[nt] = __expf(v[nt] - mx);
        sum += v[nt];
      }
      sum += __shfl_xor(sum, 1, 64);
      sum += __shfl_xor(sum, 2, 64);
      sum += __shfl_xor(sum, 4, 64);
      sum += __shfl_xor(sum, 8, 64);
      rinv[mt][r] = __builtin_amdgcn_rcpf(sum);
#pragma unroll
      for (int nt = 0; nt < 4; ++nt)
        Pl[(lg * 4 + r) * 72 + nt * 16 + lr] = f2bf(v[nt]);
    }

    // PV (in-order DS pipe: same-wave reads follow writes)
    bf16x8 pa[2];
#pragma unroll
    for (int ki = 0; ki < 2; ++ki)
      pa[ki] = *(const bf16x8*)(Pl + lr * 72 + ki * 32 + lg * 8);
    __builtin_amdgcn_s_setprio(1);
#pragma unroll
    for (int dt = 0; dt < 2; ++dt)
#pragma unroll
      for (int ki = 0; ki < 2; ++ki)
        o[mt][dt] = __builtin_amdgcn_mfma_f32_16x16x32_bf16(pa[ki], vfrag[dt][ki], o[mt][dt], 0, 0, 0);
    __builtin_amdgcn_s_setprio(0);
  }

#pragma unroll
  for (int mt = 0; mt < 4; ++mt) {
#pragma unroll
    for (int r = 0; r < 4; ++r) {
      const int m = mt * 16 + lg * 4 + r;
      const float ri = rinv[mt][r];
#pragma unroll
      for (int dt = 0; dt < 2; ++dt) {
        const int d = dt * 16 + lr;
        attn_out[(size_t)(b * 64 + m) * 512 + h * 32 + d] = f2bf(o[mt][dt][r] * ri);
      }
    }
  }
}

// ---------------- launch ----------------
extern "C" void kernel_launch(void* const* d_in, const int* in_sizes, int n_in,
                              void* d_out, int out_size, void* d_ws, size_t ws_size,
                              hipStream_t stream) {
  const float* X = (const float*)d_in[0];
  const float* mask = (const float*)d_in[1];
  const float* qkv_w = (const float*)d_in[2];
  const float* qkv_b = (const float*)d_in[3];
  const float* proj_w = (const float*)d_in[4];
  const float* proj_b = (const float*)d_in[5];
  const float* bias_table = (const float*)d_in[6];
  float* out = (float*)d_out;
  char* ws = (char*)d_ws;

  // workspace layout (bytes)
  unsigned short* Xb      = (unsigned short*)(ws);                 // 134,217,728
  unsigned short* Qh      = (unsigned short*)(ws + 134217728ull);  // 134,217,728
  unsigned short* Kh      = (unsigned short*)(ws + 268435456ull);  // 134,217,728
  unsigned short* Vh      = (unsigned short*)(ws + 402653184ull);  // 134,217,728
  unsigned short* attnout = (unsigned short*)(ws + 536870912ull);  // 134,217,728
  unsigned short* qkv_wb  = (unsigned short*)(ws + 671088640ull);  // 1,572,864
  unsigned short* proj_wb = (unsigned short*)(ws + 672661504ull);  // 524,288
  float*          Mf      = (float*)(ws + 673185792ull);           // 16,777,216

  f32_to_bf16_vec4<<<2048, 256, 0, stream>>>(X, Xb, 67108864 / 4);
  f32_to_bf16_vec4<<<768, 256, 0, stream>>>(qkv_w, qkv_wb, 786432 / 4);
  f32_to_bf16_vec4<<<256, 256, 0, stream>>>(proj_w, proj_wb, 262144 / 4);
  build_bias_mask<<<16384, 256, 0, stream>>>(bias_table, mask, Mf);

  // QKV: M=131072, N=1536, K=512 -> head-blocked Q/K/V bf16; grid 512*6 = 3072
  gemm256<6, 2><<<3072, 512, 0, stream>>>(Xb, qkv_wb, qkv_b, (void*)Qh, (void*)Kh, (void*)Vh, 1536);

  // attention: 2 waves per block, window-paired (same b&63, same h) share the M slice
  attn_kernel<<<16384, 128, 0, stream>>>(Qh, Kh, Vh, Mf, attnout);

  // proj: M=131072, N=512, K=512 -> d_out f32; grid 512*2 = 1024
  gemm256<2, 0><<<1024, 512, 0, stream>>>(attnout, proj_wb, proj_b, (void*)out, nullptr, nullptr, 512);
}

// Round 16
// 568.211 us; speedup vs baseline: 1.1830x; 1.0238x over previous
//
#include <hip/hip_runtime.h>

typedef __bf16 bf16x8 __attribute__((ext_vector_type(8)));
typedef float f32x4 __attribute__((ext_vector_type(4)));

__device__ __forceinline__ unsigned short f2bf(float x) {
  union { float f; unsigned int u; } c; c.f = x;
  unsigned int r = c.u + 0x7FFFu + ((c.u >> 16) & 1u);
  return (unsigned short)(r >> 16);
}

__device__ __forceinline__ float bf2f(unsigned short u) {
  union { unsigned int ui; float f; } c; c.ui = ((unsigned int)u) << 16;
  return c.f;
}

// ---------------- convert f32 -> bf16 (X only; big, BW-bound) ----------------
__global__ __launch_bounds__(256) void f32_to_bf16_vec4(
    const float* __restrict__ in, unsigned short* __restrict__ out, int n4) {
  int i = blockIdx.x * blockDim.x + threadIdx.x;
  int stride = gridDim.x * blockDim.x;
  const float4* in4 = (const float4*)in;
  ushort4* out4 = (ushort4*)out;
  for (; i < n4; i += stride) {
    float4 f = in4[i];
    ushort4 u;
    u.x = f2bf(f.x); u.y = f2bf(f.y); u.z = f2bf(f.z); u.w = f2bf(f.w);
    out4[i] = u;
  }
}

// ---------------- merged prep: weight converts + bf16 bias+mask table ----------------
// blocks [0,768): qkv_w f32->bf16 (196608 float4)
// blocks [768,1024): proj_w f32->bf16 (65536 float4)
// blocks [1024,17408): M[w][h][q][k] = bf16(bias_table[q-k+63][h] + mask[w][q][k])
__global__ __launch_bounds__(256) void prep_kernel(
    const float* __restrict__ qkv_w, unsigned short* __restrict__ qkv_wb,
    const float* __restrict__ proj_w, unsigned short* __restrict__ proj_wb,
    const float* __restrict__ bias_table, const float* __restrict__ mask,
    unsigned short* __restrict__ Mb) {
  const int bid = blockIdx.x;
  if (bid < 768) {
    const int i = bid * 256 + threadIdx.x;
    float4 f = ((const float4*)qkv_w)[i];
    ushort4 u;
    u.x = f2bf(f.x); u.y = f2bf(f.y); u.z = f2bf(f.z); u.w = f2bf(f.w);
    ((ushort4*)qkv_wb)[i] = u;
  } else if (bid < 1024) {
    const int i = (bid - 768) * 256 + threadIdx.x;
    float4 f = ((const float4*)proj_w)[i];
    ushort4 u;
    u.x = f2bf(f.x); u.y = f2bf(f.y); u.z = f2bf(f.z); u.w = f2bf(f.w);
    ((ushort4*)proj_wb)[i] = u;
  } else {
    const int idx = (bid - 1024) * 256 + threadIdx.x;
    const int k = idx & 63, q = (idx >> 6) & 63, h = (idx >> 12) & 15, w = idx >> 16;
    Mb[idx] = f2bf(bias_table[(q - k + 63) * 16 + h] + mask[(w * 64 + q) * 64 + k]);
  }
}

#define GLOAD_LDS16(gp, lp)                                                          \
  __builtin_amdgcn_global_load_lds(                                                  \
      (const __attribute__((address_space(1))) unsigned int*)(uintptr_t)(gp),        \
      (__attribute__((address_space(3))) unsigned int*)(uintptr_t)(lp), 16, 0, 0)

// ---------------- 256x256 GEMM, 16x16x32 MFMA, 4 phases/K-tile (round-5 schedule) ----
// EPI: 0 = f32 row-major out (C0, ldc); 2 = qkv-split head-blocked bf16 out (C0=Q,C1=K,C2=V)
template <int NBN, int EPI>
__global__ __launch_bounds__(512, 2) void gemm256(
    const unsigned short* __restrict__ A,
    const unsigned short* __restrict__ B,
    const float* __restrict__ bias,
    void* __restrict__ C0, void* __restrict__ C1, void* __restrict__ C2,
    int ldc) {
  constexpr int K = 512;
  constexpr int NT = K / 64;  // 8 K-tiles
  __shared__ __attribute__((aligned(128))) char lds[131072];

  const int t = threadIdx.x;
  const int lane = t & 63;
  const int wid = t >> 6;
  const int wr = wid >> 2, wc = wid & 3;
  const int lr = lane & 15, lg = lane >> 4;

  const int nwg = gridDim.x;
  const int cpx = nwg >> 3;
  const int wgid = (blockIdx.x & 7) * cpx + (blockIdx.x >> 3);
  const int bm = wgid / NBN, bn = wgid % NBN;
  const int m0 = bm * 256, n0 = bn * 256;

  const char* Ab = (const char*)(A + (size_t)m0 * K);
  const char* Bb = (const char*)(B + (size_t)n0 * K);

  const int r3 = t >> 3, ps = t & 7;

  unsigned aoff[2][2], adst[2][2], boff[2][2], bdst[2][2];
#pragma unroll
  for (int j = 0; j < 2; ++j)
#pragma unroll
    for (int i = 0; i < 2; ++i) {
      const int rowA = i * 128 + j * 64 + r3;
      aoff[j][i] = (unsigned)((rowA * K + ((ps ^ (rowA & 7)) << 3)) * 2);
      adst[j][i] = (unsigned)(rowA * 128 + ps * 16);
      const int rowB = i * 128 + ((r3 >> 5) << 6) + j * 32 + (r3 & 31);
      boff[j][i] = (unsigned)((rowB * K + ((ps ^ (rowB & 7)) << 3)) * 2);
      bdst[j][i] = (unsigned)(65536 + rowB * 128 + ps * 16);
    }

#define STAGE_A(j, tt, buf)                                                   \
  do {                                                                        \
    GLOAD_LDS16(Ab + aoff[j][0] + (tt)*128, lds + (buf)*32768 + adst[j][0]);  \
    GLOAD_LDS16(Ab + aoff[j][1] + (tt)*128, lds + (buf)*32768 + adst[j][1]);  \
  } while (0)
#define STAGE_B(j, tt, buf)                                                   \
  do {                                                                        \
    GLOAD_LDS16(Bb + boff[j][0] + (tt)*128, lds + (buf)*32768 + bdst[j][0]);  \
    GLOAD_LDS16(Bb + boff[j][1] + (tt)*128, lds + (buf)*32768 + bdst[j][1]);  \
  } while (0)

  unsigned abase[2], bbase[2];
#pragma unroll
  for (int kk = 0; kk < 2; ++kk) {
    abase[kk] = (unsigned)((wr * 128 + lr) * 128 + (((kk * 4 + lg) ^ (lr & 7)) << 4));
    bbase[kk] = (unsigned)(65536 + (wc * 64 + lr) * 128 + (((kk * 4 + lg) ^ (lr & 7)) << 4));
  }

  f32x4 acc[8][4];
#pragma unroll
  for (int i = 0; i < 8; ++i)
#pragma unroll
    for (int j = 0; j < 4; ++j) acc[i][j] = f32x4{0.f, 0.f, 0.f, 0.f};

#define BAR_IN()                                         \
  __builtin_amdgcn_s_barrier();                          \
  asm volatile("s_waitcnt lgkmcnt(0)" ::: "memory");     \
  __builtin_amdgcn_sched_barrier(0);                     \
  __builtin_amdgcn_s_setprio(1)
#define MFMA16(QM, NTLO)                                                            \
  _Pragma("unroll") for (int mt = 0; mt < 4; ++mt)                                  \
    _Pragma("unroll") for (int nt = 0; nt < 2; ++nt)                                \
      _Pragma("unroll") for (int kk = 0; kk < 2; ++kk)                              \
        acc[(QM)*4 + mt][(NTLO) + nt] = __builtin_amdgcn_mfma_f32_16x16x32_bf16(    \
            af[mt][kk], bfr[(NTLO) + nt][kk], acc[(QM)*4 + mt][(NTLO) + nt], 0, 0, 0)

  // prologue: UA0(t0) UB0(t0) UB1(t0) UA1(t0) UA0(t1) UB0(t1)  (12 loads)
  STAGE_A(0, 0, 0); STAGE_B(0, 0, 0); STAGE_B(1, 0, 0); STAGE_A(1, 0, 0);
  STAGE_A(0, 1, 1); STAGE_B(0, 1, 1);
  asm volatile("s_waitcnt vmcnt(8)" ::: "memory");
  __builtin_amdgcn_s_barrier();

  // Deaths (tile tt, buf): UA0,UB0 after p0; UB1 after p1; UA1 after p2.
  // Stage: p0->UB1(tt+1,nb), p1->UA1(tt+1,nb), p2->UA0(tt+2,buf), p3->UB0(tt+2,buf).
#pragma unroll
  for (int tt = 0; tt < NT; ++tt) {
    const int buf = tt & 1;
    const int nb = buf ^ 1;
    bf16x8 af[4][2], bfr[4][2];
    // ---- p0 ----
#pragma unroll
    for (int nt = 0; nt < 2; ++nt)
#pragma unroll
      for (int kk = 0; kk < 2; ++kk)
        bfr[nt][kk] = *(const bf16x8*)(lds + buf * 32768 + bbase[kk] + nt * 2048);
#pragma unroll
    for (int mt = 0; mt < 4; ++mt)
#pragma unroll
      for (int kk = 0; kk < 2; ++kk)
        af[mt][kk] = *(const bf16x8*)(lds + buf * 32768 + abase[kk] + mt * 2048);
    if (tt + 1 < NT) STAGE_B(1, tt + 1, nb);
    BAR_IN();
    MFMA16(0, 0);
    __builtin_amdgcn_s_setprio(0);
    if (tt == NT - 1) asm volatile("s_waitcnt vmcnt(2)" ::: "memory");
    else              asm volatile("s_waitcnt vmcnt(8)" ::: "memory");
    __builtin_amdgcn_s_barrier();
    // ---- p1 ----
#pragma unroll
    for (int nt = 2; nt < 4; ++nt)
#pragma unroll
      for (int kk = 0; kk < 2; ++kk)
        bfr[nt][kk] = *(const bf16x8*)(lds + buf * 32768 + bbase[kk] + nt * 2048);
    if (tt + 1 < NT) STAGE_A(1, tt + 1, nb);
    BAR_IN();
    MFMA16(0, 2);
    __builtin_amdgcn_s_setprio(0);
    if (tt == NT - 1) asm volatile("s_waitcnt vmcnt(0)" ::: "memory");
    else              asm volatile("s_waitcnt vmcnt(8)" ::: "memory");
    __builtin_amdgcn_s_barrier();
    // ---- p2 ----
#pragma unroll
    for (int mt = 0; mt < 4; ++mt)
#pragma unroll
      for (int kk = 0; kk < 2; ++kk)
        af[mt][kk] = *(const bf16x8*)(lds + buf * 32768 + abase[kk] + 8192 + mt * 2048);
    if (tt + 2 < NT) STAGE_A(0, tt + 2, buf);
    BAR_IN();
    MFMA16(1, 0);
    __builtin_amdgcn_s_setprio(0);
    if (tt < NT - 1) asm volatile("s_waitcnt vmcnt(8)" ::: "memory");
    __builtin_amdgcn_s_barrier();
    // ---- p3 ----
    if (tt + 2 < NT) STAGE_B(0, tt + 2, buf);
    BAR_IN();
    MFMA16(1, 2);
    __builtin_amdgcn_s_setprio(0);
    if (tt < NT - 2)       asm volatile("s_waitcnt vmcnt(8)" ::: "memory");
    else if (tt == NT - 2) asm volatile("s_waitcnt vmcnt(4)" ::: "memory");
    __builtin_amdgcn_s_barrier();
  }
#undef MFMA16
#undef BAR_IN
#undef STAGE_A
#undef STAGE_B

  // epilogue: 16x16 C/D layout: col = lr, row = lg*4 + r
#pragma unroll
  for (int qm = 0; qm < 2; ++qm)
#pragma unroll
    for (int mt = 0; mt < 4; ++mt)
#pragma unroll
      for (int nt = 0; nt < 4; ++nt) {
        const int n = n0 + wc * 64 + nt * 16 + lr;
        const float bv = bias[n];
        const f32x4 a4 = acc[qm * 4 + mt][nt];
        if constexpr (EPI == 2) {
          const int part = n >> 9;
          unsigned short* dst = part == 0 ? (unsigned short*)C0
                                 : (part == 1 ? (unsigned short*)C1 : (unsigned short*)C2);
          const float sc = (part == 0) ? 0.17677669529663687f : 1.0f;
          const int hh = (n >> 5) & 15, dd = n & 31;
#pragma unroll
          for (int r = 0; r < 4; ++r) {
            const int m = m0 + wr * 128 + qm * 64 + mt * 16 + lg * 4 + r;
            dst[((size_t)((m >> 6) * 16 + hh) * 64 + (m & 63)) * 32 + dd] =
                f2bf((a4[r] + bv) * sc);
          }
        } else {
#pragma unroll
          for (int r = 0; r < 4; ++r) {
            const int m = m0 + wr * 128 + qm * 64 + mt * 16 + lg * 4 + r;
            ((float*)C0)[(size_t)m * ldc + n] = a4[r] + bv;
          }
        }
      }
}

// ---------------- fused window attention v3 + setprio + bf16 M table ----------------
// 128 threads = 2 waves, wave w handles (b,h) = blockIdx.x*2+w. No barriers (per-wave LDS).
__global__ __launch_bounds__(128) void attn_kernel(
    const unsigned short* __restrict__ Qh,  // [32768][64][32] bf16, pre-scaled
    const unsigned short* __restrict__ Kh,  // [32768][64][32]
    const unsigned short* __restrict__ Vh,  // [32768][64][32]
    const unsigned short* __restrict__ M,   // [64][16][64][64] bf16 fused bias+mask
    unsigned short* __restrict__ attn_out   // [131072][512] bf16, col = h*32+d
) {
  const int wv = threadIdx.x >> 6;
  const int bh = blockIdx.x * 2 + wv;
  const int b = bh >> 4, h = bh & 15;
  const int lane = threadIdx.x & 63;
  const int lr = lane & 15, lg = lane >> 4;

  __shared__ unsigned short VtS[2][32 * 72];  // V^T per wave: [d][k], stride 72
  __shared__ unsigned short PlS[2][16 * 72];  // P-slice per wave: [16 q][k]
  unsigned short* Vt = VtS[wv];
  unsigned short* Pl = PlS[wv];

  const unsigned short* qb = Qh + (size_t)bh * 2048;
  const unsigned short* kb = Kh + (size_t)bh * 2048;
  const unsigned short* vg = Vh + (size_t)bh * 2048;

  bf16x8 vr[4];
#pragma unroll
  for (int i = 0; i < 4; ++i) vr[i] = ((const bf16x8*)(vg + lane * 32))[i];
  bf16x8 kf[4], qf[4];
#pragma unroll
  for (int nt = 0; nt < 4; ++nt)
    kf[nt] = *(const bf16x8*)(kb + (nt * 16 + lr) * 32 + lg * 8);
#pragma unroll
  for (int mt = 0; mt < 4; ++mt)
    qf[mt] = *(const bf16x8*)(qb + (mt * 16 + lr) * 32 + lg * 8);

  {
    __bf16* vt = (__bf16*)Vt;
#pragma unroll
    for (int d = 0; d < 8; ++d) {
      vt[(d)*72 + lane] = vr[0][d];
      vt[(d + 8) * 72 + lane] = vr[1][d];
      vt[(d + 16) * 72 + lane] = vr[2][d];
      vt[(d + 24) * 72 + lane] = vr[3][d];
    }
  }
  bf16x8 vfrag[2][2];
#pragma unroll
  for (int dt = 0; dt < 2; ++dt)
#pragma unroll
    for (int ki = 0; ki < 2; ++ki)
      vfrag[dt][ki] = *(const bf16x8*)(Vt + (dt * 16 + lr) * 72 + ki * 32 + lg * 8);

  const unsigned short* Mb = M + (size_t)((b & 63) * 16 + h) * 4096;

  f32x4 o[4][2];
#pragma unroll
  for (int i = 0; i < 4; ++i)
#pragma unroll
    for (int j = 0; j < 2; ++j) o[i][j] = f32x4{0.f, 0.f, 0.f, 0.f};
  float rinv[4][4];

#pragma unroll
  for (int mt = 0; mt < 4; ++mt) {
    // coalesced bf16 M reads (lanes 0-15 contiguous per (r,nt)); half the stream vs f32
    float mv[4][4];
#pragma unroll
    for (int r = 0; r < 4; ++r)
#pragma unroll
      for (int nt = 0; nt < 4; ++nt)
        mv[r][nt] = bf2f(Mb[(mt * 16 + lg * 4 + r) * 64 + nt * 16 + lr]);

    f32x4 s[4];
#pragma unroll
    for (int nt = 0; nt < 4; ++nt) s[nt] = f32x4{0.f, 0.f, 0.f, 0.f};
    __builtin_amdgcn_s_setprio(1);
#pragma unroll
    for (int nt = 0; nt < 4; ++nt)
      s[nt] = __builtin_amdgcn_mfma_f32_16x16x32_bf16(qf[mt], kf[nt], s[nt], 0, 0, 0);
    __builtin_amdgcn_s_setprio(0);

    // v3 softmax: max-sub; sum/rcp OFF the P path (P unnormalized, rinv applied at end)
#pragma unroll
    for (int r = 0; r < 4; ++r) {
      float v[4];
#pragma unroll
      for (int nt = 0; nt < 4; ++nt) v[nt] = s[nt][r] + mv[r][nt];
      float mx = fmaxf(fmaxf(v[0], v[1]), fmaxf(v[2], v[3]));
      mx = fmaxf(mx, __shfl_xor(mx, 1, 64));
      mx = fmaxf(mx, __shfl_xor(mx, 2, 64));
      mx = fmaxf(mx, __shfl_xor(mx, 4, 64));
      mx = fmaxf(mx, __shfl_xor(mx, 8, 64));
      float sum = 0.f;
#pragma unroll
      for (int nt = 0; nt < 4; ++nt) {
        v[nt] = __expf(v[nt] - mx);
        sum += v[nt];
      }
      sum += __shfl_xor(sum, 1, 64);
      sum += __shfl_xor(sum, 2, 64);
      sum += __shfl_xor(sum, 4, 64);
      sum += __shfl_xor(sum, 8, 64);
      rinv[mt][r] = __builtin_amdgcn_rcpf(sum);
#pragma unroll
      for (int nt = 0; nt < 4; ++nt)
        Pl[(lg * 4 + r) * 72 + nt * 16 + lr] = f2bf(v[nt]);
    }

    // PV (in-order DS pipe: same-wave reads follow writes)
    bf16x8 pa[2];
#pragma unroll
    for (int ki = 0; ki < 2; ++ki)
      pa[ki] = *(const bf16x8*)(Pl + lr * 72 + ki * 32 + lg * 8);
    __builtin_amdgcn_s_setprio(1);
#pragma unroll
    for (int dt = 0; dt < 2; ++dt)
#pragma unroll
      for (int ki = 0; ki < 2; ++ki)
        o[mt][dt] = __builtin_amdgcn_mfma_f32_16x16x32_bf16(pa[ki], vfrag[dt][ki], o[mt][dt], 0, 0, 0);
    __builtin_amdgcn_s_setprio(0);
  }

#pragma unroll
  for (int mt = 0; mt < 4; ++mt) {
#pragma unroll
    for (int r = 0; r < 4; ++r) {
      const int m = mt * 16 + lg * 4 + r;
      const float ri = rinv[mt][r];
#pragma unroll
      for (int dt = 0; dt < 2; ++dt) {
        const int d = dt * 16 + lr;
        attn_out[(size_t)(b * 64 + m) * 512 + h * 32 + d] = f2bf(o[mt][dt][r] * ri);
      }
    }
  }
}

// ---------------- launch ----------------
extern "C" void kernel_launch(void* const* d_in, const int* in_sizes, int n_in,
                              void* d_out, int out_size, void* d_ws, size_t ws_size,
                              hipStream_t stream) {
  const float* X = (const float*)d_in[0];
  const float* mask = (const float*)d_in[1];
  const float* qkv_w = (const float*)d_in[2];
  const float* qkv_b = (const float*)d_in[3];
  const float* proj_w = (const float*)d_in[4];
  const float* proj_b = (const float*)d_in[5];
  const float* bias_table = (const float*)d_in[6];
  float* out = (float*)d_out;
  char* ws = (char*)d_ws;

  // workspace layout (bytes)
  unsigned short* Xb      = (unsigned short*)(ws);                 // 134,217,728
  unsigned short* Qh      = (unsigned short*)(ws + 134217728ull);  // 134,217,728
  unsigned short* Kh      = (unsigned short*)(ws + 268435456ull);  // 134,217,728
  unsigned short* Vh      = (unsigned short*)(ws + 402653184ull);  // 134,217,728
  unsigned short* attnout = (unsigned short*)(ws + 536870912ull);  // 134,217,728
  unsigned short* qkv_wb  = (unsigned short*)(ws + 671088640ull);  // 1,572,864
  unsigned short* proj_wb = (unsigned short*)(ws + 672661504ull);  // 524,288
  unsigned short* Mbf     = (unsigned short*)(ws + 673185792ull);  // 8,388,608 (bf16)

  f32_to_bf16_vec4<<<2048, 256, 0, stream>>>(X, Xb, 67108864 / 4);
  prep_kernel<<<17408, 256, 0, stream>>>(qkv_w, qkv_wb, proj_w, proj_wb,
                                         bias_table, mask, Mbf);

  // QKV: M=131072, N=1536, K=512 -> head-blocked Q/K/V bf16; grid 512*6 = 3072
  gemm256<6, 2><<<3072, 512, 0, stream>>>(Xb, qkv_wb, qkv_b, (void*)Qh, (void*)Kh, (void*)Vh, 1536);

  // attention: 2 waves per block, wave per (b,h)
  attn_kernel<<<16384, 128, 0, stream>>>(Qh, Kh, Vh, Mbf, attnout);

  // proj: M=131072, N=512, K=512 -> d_out f32; grid 512*2 = 1024
  gemm256<2, 0><<<1024, 512, 0, stream>>>(attnout, proj_wb, proj_b, (void*)out, nullptr, nullptr, 512);
}

// Round 17
// 566.510 us; speedup vs baseline: 1.1866x; 1.0030x over previous
//
#include <hip/hip_runtime.h>

typedef __bf16 bf16x8 __attribute__((ext_vector_type(8)));
typedef float f32x4 __attribute__((ext_vector_type(4)));

__device__ __forceinline__ unsigned short f2bf(float x) {
  union { float f; unsigned int u; } c; c.f = x;
  unsigned int r = c.u + 0x7FFFu + ((c.u >> 16) & 1u);
  return (unsigned short)(r >> 16);
}

__device__ __forceinline__ float bf2f(unsigned short u) {
  union { unsigned int ui; float f; } c; c.ui = ((unsigned int)u) << 16;
  return c.f;
}

// ---------------- merged prep: X convert + weight converts + bf16 bias+mask table ----
// blocks [0,2048):      X f32->bf16, grid-stride over 16777216 float4 (32 iters/thread)
// blocks [2048,2816):   qkv_w f32->bf16 (196608 float4)
// blocks [2816,3072):   proj_w f32->bf16 (65536 float4)
// blocks [3072,19456):  M[w][h][q][k] = bf16(bias_table[q-k+63][h] + mask[w][q][k])
__global__ __launch_bounds__(256) void prep_kernel(
    const float* __restrict__ X, unsigned short* __restrict__ Xb,
    const float* __restrict__ qkv_w, unsigned short* __restrict__ qkv_wb,
    const float* __restrict__ proj_w, unsigned short* __restrict__ proj_wb,
    const float* __restrict__ bias_table, const float* __restrict__ mask,
    unsigned short* __restrict__ Mb) {
  const int bid = blockIdx.x;
  if (bid < 2048) {
    const float4* in4 = (const float4*)X;
    ushort4* out4 = (ushort4*)Xb;
    for (int i = bid * 256 + threadIdx.x; i < 16777216; i += 2048 * 256) {
      float4 f = in4[i];
      ushort4 u;
      u.x = f2bf(f.x); u.y = f2bf(f.y); u.z = f2bf(f.z); u.w = f2bf(f.w);
      out4[i] = u;
    }
  } else if (bid < 2816) {
    const int i = (bid - 2048) * 256 + threadIdx.x;
    float4 f = ((const float4*)qkv_w)[i];
    ushort4 u;
    u.x = f2bf(f.x); u.y = f2bf(f.y); u.z = f2bf(f.z); u.w = f2bf(f.w);
    ((ushort4*)qkv_wb)[i] = u;
  } else if (bid < 3072) {
    const int i = (bid - 2816) * 256 + threadIdx.x;
    float4 f = ((const float4*)proj_w)[i];
    ushort4 u;
    u.x = f2bf(f.x); u.y = f2bf(f.y); u.z = f2bf(f.z); u.w = f2bf(f.w);
    ((ushort4*)proj_wb)[i] = u;
  } else {
    const int idx = (bid - 3072) * 256 + threadIdx.x;
    const int k = idx & 63, q = (idx >> 6) & 63, h = (idx >> 12) & 15, w = idx >> 16;
    Mb[idx] = f2bf(bias_table[(q - k + 63) * 16 + h] + mask[(w * 64 + q) * 64 + k]);
  }
}

#define GLOAD_LDS16(gp, lp)                                                          \
  __builtin_amdgcn_global_load_lds(                                                  \
      (const __attribute__((address_space(1))) unsigned int*)(uintptr_t)(gp),        \
      (__attribute__((address_space(3))) unsigned int*)(uintptr_t)(lp), 16, 0, 0)

// ---------------- 256x256 GEMM, 16x16x32 MFMA, 4 phases/K-tile (round-5 schedule) ----
// EPI: 0 = f32 row-major out (C0, ldc); 2 = qkv-split head-blocked bf16 out (C0=Q,C1=K,C2=V)
template <int NBN, int EPI>
__global__ __launch_bounds__(512, 2) void gemm256(
    const unsigned short* __restrict__ A,
    const unsigned short* __restrict__ B,
    const float* __restrict__ bias,
    void* __restrict__ C0, void* __restrict__ C1, void* __restrict__ C2,
    int ldc) {
  constexpr int K = 512;
  constexpr int NT = K / 64;  // 8 K-tiles
  __shared__ __attribute__((aligned(128))) char lds[131072];

  const int t = threadIdx.x;
  const int lane = t & 63;
  const int wid = t >> 6;
  const int wr = wid >> 2, wc = wid & 3;
  const int lr = lane & 15, lg = lane >> 4;

  const int nwg = gridDim.x;
  const int cpx = nwg >> 3;
  const int wgid = (blockIdx.x & 7) * cpx + (blockIdx.x >> 3);
  const int bm = wgid / NBN, bn = wgid % NBN;
  const int m0 = bm * 256, n0 = bn * 256;

  const char* Ab = (const char*)(A + (size_t)m0 * K);
  const char* Bb = (const char*)(B + (size_t)n0 * K);

  const int r3 = t >> 3, ps = t & 7;

  unsigned aoff[2][2], adst[2][2], boff[2][2], bdst[2][2];
#pragma unroll
  for (int j = 0; j < 2; ++j)
#pragma unroll
    for (int i = 0; i < 2; ++i) {
      const int rowA = i * 128 + j * 64 + r3;
      aoff[j][i] = (unsigned)((rowA * K + ((ps ^ (rowA & 7)) << 3)) * 2);
      adst[j][i] = (unsigned)(rowA * 128 + ps * 16);
      const int rowB = i * 128 + ((r3 >> 5) << 6) + j * 32 + (r3 & 31);
      boff[j][i] = (unsigned)((rowB * K + ((ps ^ (rowB & 7)) << 3)) * 2);
      bdst[j][i] = (unsigned)(65536 + rowB * 128 + ps * 16);
    }

#define STAGE_A(j, tt, buf)                                                   \
  do {                                                                        \
    GLOAD_LDS16(Ab + aoff[j][0] + (tt)*128, lds + (buf)*32768 + adst[j][0]);  \
    GLOAD_LDS16(Ab + aoff[j][1] + (tt)*128, lds + (buf)*32768 + adst[j][1]);  \
  } while (0)
#define STAGE_B(j, tt, buf)                                                   \
  do {                                                                        \
    GLOAD_LDS16(Bb + boff[j][0] + (tt)*128, lds + (buf)*32768 + bdst[j][0]);  \
    GLOAD_LDS16(Bb + boff[j][1] + (tt)*128, lds + (buf)*32768 + bdst[j][1]);  \
  } while (0)

  unsigned abase[2], bbase[2];
#pragma unroll
  for (int kk = 0; kk < 2; ++kk) {
    abase[kk] = (unsigned)((wr * 128 + lr) * 128 + (((kk * 4 + lg) ^ (lr & 7)) << 4));
    bbase[kk] = (unsigned)(65536 + (wc * 64 + lr) * 128 + (((kk * 4 + lg) ^ (lr & 7)) << 4));
  }

  f32x4 acc[8][4];
#pragma unroll
  for (int i = 0; i < 8; ++i)
#pragma unroll
    for (int j = 0; j < 4; ++j) acc[i][j] = f32x4{0.f, 0.f, 0.f, 0.f};

#define BAR_IN()                                         \
  __builtin_amdgcn_s_barrier();                          \
  asm volatile("s_waitcnt lgkmcnt(0)" ::: "memory");     \
  __builtin_amdgcn_sched_barrier(0);                     \
  __builtin_amdgcn_s_setprio(1)
#define MFMA16(QM, NTLO)                                                            \
  _Pragma("unroll") for (int mt = 0; mt < 4; ++mt)                                  \
    _Pragma("unroll") for (int nt = 0; nt < 2; ++nt)                                \
      _Pragma("unroll") for (int kk = 0; kk < 2; ++kk)                              \
        acc[(QM)*4 + mt][(NTLO) + nt] = __builtin_amdgcn_mfma_f32_16x16x32_bf16(    \
            af[mt][kk], bfr[(NTLO) + nt][kk], acc[(QM)*4 + mt][(NTLO) + nt], 0, 0, 0)

  // prologue: UA0(t0) UB0(t0) UB1(t0) UA1(t0) UA0(t1) UB0(t1)  (12 loads)
  STAGE_A(0, 0, 0); STAGE_B(0, 0, 0); STAGE_B(1, 0, 0); STAGE_A(1, 0, 0);
  STAGE_A(0, 1, 1); STAGE_B(0, 1, 1);
  asm volatile("s_waitcnt vmcnt(8)" ::: "memory");
  __builtin_amdgcn_s_barrier();

  // Deaths (tile tt, buf): UA0,UB0 after p0; UB1 after p1; UA1 after p2.
  // Stage: p0->UB1(tt+1,nb), p1->UA1(tt+1,nb), p2->UA0(tt+2,buf), p3->UB0(tt+2,buf).
#pragma unroll
  for (int tt = 0; tt < NT; ++tt) {
    const int buf = tt & 1;
    const int nb = buf ^ 1;
    bf16x8 af[4][2], bfr[4][2];
    // ---- p0 ----
#pragma unroll
    for (int nt = 0; nt < 2; ++nt)
#pragma unroll
      for (int kk = 0; kk < 2; ++kk)
        bfr[nt][kk] = *(const bf16x8*)(lds + buf * 32768 + bbase[kk] + nt * 2048);
#pragma unroll
    for (int mt = 0; mt < 4; ++mt)
#pragma unroll
      for (int kk = 0; kk < 2; ++kk)
        af[mt][kk] = *(const bf16x8*)(lds + buf * 32768 + abase[kk] + mt * 2048);
    if (tt + 1 < NT) STAGE_B(1, tt + 1, nb);
    BAR_IN();
    MFMA16(0, 0);
    __builtin_amdgcn_s_setprio(0);
    if (tt == NT - 1) asm volatile("s_waitcnt vmcnt(2)" ::: "memory");
    else              asm volatile("s_waitcnt vmcnt(8)" ::: "memory");
    __builtin_amdgcn_s_barrier();
    // ---- p1 ----
#pragma unroll
    for (int nt = 2; nt < 4; ++nt)
#pragma unroll
      for (int kk = 0; kk < 2; ++kk)
        bfr[nt][kk] = *(const bf16x8*)(lds + buf * 32768 + bbase[kk] + nt * 2048);
    if (tt + 1 < NT) STAGE_A(1, tt + 1, nb);
    BAR_IN();
    MFMA16(0, 2);
    __builtin_amdgcn_s_setprio(0);
    if (tt == NT - 1) asm volatile("s_waitcnt vmcnt(0)" ::: "memory");
    else              asm volatile("s_waitcnt vmcnt(8)" ::: "memory");
    __builtin_amdgcn_s_barrier();
    // ---- p2 ----
#pragma unroll
    for (int mt = 0; mt < 4; ++mt)
#pragma unroll
      for (int kk = 0; kk < 2; ++kk)
        af[mt][kk] = *(const bf16x8*)(lds + buf * 32768 + abase[kk] + 8192 + mt * 2048);
    if (tt + 2 < NT) STAGE_A(0, tt + 2, buf);
    BAR_IN();
    MFMA16(1, 0);
    __builtin_amdgcn_s_setprio(0);
    if (tt < NT - 1) asm volatile("s_waitcnt vmcnt(8)" ::: "memory");
    __builtin_amdgcn_s_barrier();
    // ---- p3 ----
    if (tt + 2 < NT) STAGE_B(0, tt + 2, buf);
    BAR_IN();
    MFMA16(1, 2);
    __builtin_amdgcn_s_setprio(0);
    if (tt < NT - 2)       asm volatile("s_waitcnt vmcnt(8)" ::: "memory");
    else if (tt == NT - 2) asm volatile("s_waitcnt vmcnt(4)" ::: "memory");
    __builtin_amdgcn_s_barrier();
  }
#undef MFMA16
#undef BAR_IN
#undef STAGE_A
#undef STAGE_B

  // epilogue: 16x16 C/D layout: col = lr, row = lg*4 + r
#pragma unroll
  for (int qm = 0; qm < 2; ++qm)
#pragma unroll
    for (int mt = 0; mt < 4; ++mt)
#pragma unroll
      for (int nt = 0; nt < 4; ++nt) {
        const int n = n0 + wc * 64 + nt * 16 + lr;
        const float bv = bias[n];
        const f32x4 a4 = acc[qm * 4 + mt][nt];
        if constexpr (EPI == 2) {
          const int part = n >> 9;
          unsigned short* dst = part == 0 ? (unsigned short*)C0
                                 : (part == 1 ? (unsigned short*)C1 : (unsigned short*)C2);
          const float sc = (part == 0) ? 0.17677669529663687f : 1.0f;
          const int hh = (n >> 5) & 15, dd = n & 31;
#pragma unroll
          for (int r = 0; r < 4; ++r) {
            const int m = m0 + wr * 128 + qm * 64 + mt * 16 + lg * 4 + r;
            dst[((size_t)((m >> 6) * 16 + hh) * 64 + (m & 63)) * 32 + dd] =
                f2bf((a4[r] + bv) * sc);
          }
        } else {
#pragma unroll
          for (int r = 0; r < 4; ++r) {
            const int m = m0 + wr * 128 + qm * 64 + mt * 16 + lg * 4 + r;
            ((float*)C0)[(size_t)m * ldc + n] = a4[r] + bv;
          }
        }
      }
}

// ---------------- fused window attention v3 + setprio + bf16 M table ----------------
// 128 threads = 2 waves, wave w handles (b,h) = blockIdx.x*2+w. No barriers (per-wave LDS).
__global__ __launch_bounds__(128) void attn_kernel(
    const unsigned short* __restrict__ Qh,  // [32768][64][32] bf16, pre-scaled
    const unsigned short* __restrict__ Kh,  // [32768][64][32]
    const unsigned short* __restrict__ Vh,  // [32768][64][32]
    const unsigned short* __restrict__ M,   // [64][16][64][64] bf16 fused bias+mask
    unsigned short* __restrict__ attn_out   // [131072][512] bf16, col = h*32+d
) {
  const int wv = threadIdx.x >> 6;
  const int bh = blockIdx.x * 2 + wv;
  const int b = bh >> 4, h = bh & 15;
  const int lane = threadIdx.x & 63;
  const int lr = lane & 15, lg = lane >> 4;

  __shared__ unsigned short VtS[2][32 * 72];  // V^T per wave: [d][k], stride 72
  __shared__ unsigned short PlS[2][16 * 72];  // P-slice per wave: [16 q][k]
  unsigned short* Vt = VtS[wv];
  unsigned short* Pl = PlS[wv];

  const unsigned short* qb = Qh + (size_t)bh * 2048;
  const unsigned short* kb = Kh + (size_t)bh * 2048;
  const unsigned short* vg = Vh + (size_t)bh * 2048;

  bf16x8 vr[4];
#pragma unroll
  for (int i = 0; i < 4; ++i) vr[i] = ((const bf16x8*)(vg + lane * 32))[i];
  bf16x8 kf[4], qf[4];
#pragma unroll
  for (int nt = 0; nt < 4; ++nt)
    kf[nt] = *(const bf16x8*)(kb + (nt * 16 + lr) * 32 + lg * 8);
#pragma unroll
  for (int mt = 0; mt < 4; ++mt)
    qf[mt] = *(const bf16x8*)(qb + (mt * 16 + lr) * 32 + lg * 8);

  {
    __bf16* vt = (__bf16*)Vt;
#pragma unroll
    for (int d = 0; d < 8; ++d) {
      vt[(d)*72 + lane] = vr[0][d];
      vt[(d + 8) * 72 + lane] = vr[1][d];
      vt[(d + 16) * 72 + lane] = vr[2][d];
      vt[(d + 24) * 72 + lane] = vr[3][d];
    }
  }
  bf16x8 vfrag[2][2];
#pragma unroll
  for (int dt = 0; dt < 2; ++dt)
#pragma unroll
    for (int ki = 0; ki < 2; ++ki)
      vfrag[dt][ki] = *(const bf16x8*)(Vt + (dt * 16 + lr) * 72 + ki * 32 + lg * 8);

  const unsigned short* Mb = M + (size_t)((b & 63) * 16 + h) * 4096;

  f32x4 o[4][2];
#pragma unroll
  for (int i = 0; i < 4; ++i)
#pragma unroll
    for (int j = 0; j < 2; ++j) o[i][j] = f32x4{0.f, 0.f, 0.f, 0.f};
  float rinv[4][4];

#pragma unroll
  for (int mt = 0; mt < 4; ++mt) {
    // coalesced bf16 M reads (lanes 0-15 contiguous per (r,nt))
    float mv[4][4];
#pragma unroll
    for (int r = 0; r < 4; ++r)
#pragma unroll
      for (int nt = 0; nt < 4; ++nt)
        mv[r][nt] = bf2f(Mb[(mt * 16 + lg * 4 + r) * 64 + nt * 16 + lr]);

    f32x4 s[4];
#pragma unroll
    for (int nt = 0; nt < 4; ++nt) s[nt] = f32x4{0.f, 0.f, 0.f, 0.f};
    __builtin_amdgcn_s_setprio(1);
#pragma unroll
    for (int nt = 0; nt < 4; ++nt)
      s[nt] = __builtin_amdgcn_mfma_f32_16x16x32_bf16(qf[mt], kf[nt], s[nt], 0, 0, 0);
    __builtin_amdgcn_s_setprio(0);

    // v3 softmax: max-sub; sum/rcp OFF the P path (P unnormalized, rinv applied at end)
#pragma unroll
    for (int r = 0; r < 4; ++r) {
      float v[4];
#pragma unroll
      for (int nt = 0; nt < 4; ++nt) v[nt] = s[nt][r] + mv[r][nt];
      float mx = fmaxf(fmaxf(v[0], v[1]), fmaxf(v[2], v[3]));
      mx = fmaxf(mx, __shfl_xor(mx, 1, 64));
      mx = fmaxf(mx, __shfl_xor(mx, 2, 64));
      mx = fmaxf(mx, __shfl_xor(mx, 4, 64));
      mx = fmaxf(mx, __shfl_xor(mx, 8, 64));
      float sum = 0.f;
#pragma unroll
      for (int nt = 0; nt < 4; ++nt) {
        v[nt] = __expf(v[nt] - mx);
        sum += v[nt];
      }
      sum += __shfl_xor(sum, 1, 64);
      sum += __shfl_xor(sum, 2, 64);
      sum += __shfl_xor(sum, 4, 64);
      sum += __shfl_xor(sum, 8, 64);
      rinv[mt][r] = __builtin_amdgcn_rcpf(sum);
#pragma unroll
      for (int nt = 0; nt < 4; ++nt)
        Pl[(lg * 4 + r) * 72 + nt * 16 + lr] = f2bf(v[nt]);
    }

    // PV (in-order DS pipe: same-wave reads follow writes)
    bf16x8 pa[2];
#pragma unroll
    for (int ki = 0; ki < 2; ++ki)
      pa[ki] = *(const bf16x8*)(Pl + lr * 72 + ki * 32 + lg * 8);
    __builtin_amdgcn_s_setprio(1);
#pragma unroll
    for (int dt = 0; dt < 2; ++dt)
#pragma unroll
      for (int ki = 0; ki < 2; ++ki)
        o[mt][dt] = __builtin_amdgcn_mfma_f32_16x16x32_bf16(pa[ki], vfrag[dt][ki], o[mt][dt], 0, 0, 0);
    __builtin_amdgcn_s_setprio(0);
  }

#pragma unroll
  for (int mt = 0; mt < 4; ++mt) {
#pragma unroll
    for (int r = 0; r < 4; ++r) {
      const int m = mt * 16 + lg * 4 + r;
      const float ri = rinv[mt][r];
#pragma unroll
      for (int dt = 0; dt < 2; ++dt) {
        const int d = dt * 16 + lr;
        attn_out[(size_t)(b * 64 + m) * 512 + h * 32 + d] = f2bf(o[mt][dt][r] * ri);
      }
    }
  }
}

// ---------------- launch ----------------
extern "C" void kernel_launch(void* const* d_in, const int* in_sizes, int n_in,
                              void* d_out, int out_size, void* d_ws, size_t ws_size,
                              hipStream_t stream) {
  const float* X = (const float*)d_in[0];
  const float* mask = (const float*)d_in[1];
  const float* qkv_w = (const float*)d_in[2];
  const float* qkv_b = (const float*)d_in[3];
  const float* proj_w = (const float*)d_in[4];
  const float* proj_b = (const float*)d_in[5];
  const float* bias_table = (const float*)d_in[6];
  float* out = (float*)d_out;
  char* ws = (char*)d_ws;

  // workspace layout (bytes)
  unsigned short* Xb      = (unsigned short*)(ws);                 // 134,217,728
  unsigned short* Qh      = (unsigned short*)(ws + 134217728ull);  // 134,217,728
  unsigned short* Kh      = (unsigned short*)(ws + 268435456ull);  // 134,217,728
  unsigned short* Vh      = (unsigned short*)(ws + 402653184ull);  // 134,217,728
  unsigned short* attnout = (unsigned short*)(ws + 536870912ull);  // 134,217,728
  unsigned short* qkv_wb  = (unsigned short*)(ws + 671088640ull);  // 1,572,864
  unsigned short* proj_wb = (unsigned short*)(ws + 672661504ull);  // 524,288
  unsigned short* Mbf     = (unsigned short*)(ws + 673185792ull);  // 8,388,608 (bf16)

  // single merged prep launch: X convert + weight converts + bf16 M table
  prep_kernel<<<19456, 256, 0, stream>>>(X, Xb, qkv_w, qkv_wb, proj_w, proj_wb,
                                         bias_table, mask, Mbf);

  // QKV: M=131072, N=1536, K=512 -> head-blocked Q/K/V bf16; grid 512*6 = 3072
  gemm256<6, 2><<<3072, 512, 0, stream>>>(Xb, qkv_wb, qkv_b, (void*)Qh, (void*)Kh, (void*)Vh, 1536);

  // attention: 2 waves per block, wave per (b,h)
  attn_kernel<<<16384, 128, 0, stream>>>(Qh, Kh, Vh, Mbf, attnout);

  // proj: M=131072, N=512, K=512 -> d_out f32; grid 512*2 = 1024
  gemm256<2, 0><<<1024, 512, 0, stream>>>(attnout, proj_wb, proj_b, (void*)out, nullptr, nullptr, 512);
}